// Round 6
// baseline (620.885 us; speedup 1.0000x reference)
//
#include <hip/hip_runtime.h>

// y[b, i] = sum v * x[b, j] + biases[i]
// 320k edges, each a dense 4x4 block at (4r, 4c); values row-major per edge.
// Round 6: per-XCD work queues. Kernel reads its real XCD via
// s_getreg(HW_REG_XCC_ID) and processes batch-windows owned by that XCD
// (window slice 5.1 MB ~ L2-resident). Work-stealing across queues keeps
// correctness independent of dispatch. Block = 4 waves x 4 quads, one window;
// 512B contiguous gathers, readfirstlane row bounds, L2-merged stores.

typedef _Float16 h2_t __attribute__((ext_vector_type(2)));

__device__ __forceinline__ h2_t as_h2(unsigned u) {
  union { unsigned u; h2_t h; } v; v.u = u; return v.h;
}

__device__ __forceinline__ float fdot2(h2_t a, h2_t b, float c) {
#if __has_builtin(__builtin_amdgcn_fdot2)
  return __builtin_amdgcn_fdot2(a, b, c, false);
#else
  return c + (float)a.x * (float)b.x + (float)a.y * (float)b.y;
#endif
}

__device__ __forceinline__ int get_xcd() {
  unsigned x;
  asm volatile("s_getreg_b32 %0, hwreg(HW_REG_XCC_ID)" : "=s"(x));
  return (int)(x & 7);
}

__global__ void hist_kernel(const int* __restrict__ indices, int* __restrict__ cnt, int E) {
  int e = blockIdx.x * blockDim.x + threadIdx.x;
  if (e >= E) return;
  int bi = indices[(size_t)e * 32];
  atomicAdd(&cnt[bi >> 2], 1);
}

// ---- parallel scan: reduce -> wave-scan of partials -> final ----
__global__ void scan_reduce_kernel(const int* __restrict__ cnt, int* __restrict__ partial, int n) {
  __shared__ int sh[256];
  int i = blockIdx.x * 256 + threadIdx.x;
  sh[threadIdx.x] = (i < n) ? cnt[i] : 0;
  __syncthreads();
  for (int off = 128; off > 0; off >>= 1) {
    if (threadIdx.x < off) sh[threadIdx.x] += sh[threadIdx.x + off];
    __syncthreads();
  }
  if (threadIdx.x == 0) partial[blockIdx.x] = sh[0];
}

__global__ void scan_mid_kernel(const int* __restrict__ partial, int* __restrict__ offs, int nb) {
  int t = threadIdx.x;
  int v = (t < nb) ? partial[t] : 0;
  for (int d = 1; d < 64; d <<= 1) {
    int u = __shfl_up(v, d);
    if (t >= d) v += u;
  }
  if (t < nb) offs[t] = v;  // inclusive
}

__global__ void scan_final_kernel(const int* __restrict__ cnt, const int* __restrict__ offs,
                                  int* __restrict__ row_start, int n) {
  __shared__ int sh[256];
  int blk = blockIdx.x;
  int i = blk * 256 + threadIdx.x;
  int v = (i < n) ? cnt[i] : 0;
  sh[threadIdx.x] = v;
  __syncthreads();
  for (int off = 1; off < 256; off <<= 1) {
    int add = (threadIdx.x >= off) ? sh[threadIdx.x - off] : 0;
    __syncthreads();
    sh[threadIdx.x] += add;
    __syncthreads();
  }
  int base = (blk == 0) ? 0 : offs[blk - 1];
  if (i < n) row_start[i + 1] = sh[threadIdx.x] + base;
  if (blk == 0 && threadIdx.x == 0) row_start[0] = 0;
}

__global__ void scan_kernel(const int* __restrict__ cnt, int* __restrict__ row_start, int n) {
  __shared__ int buf[1024];
  __shared__ int carry_s;
  int t = threadIdx.x;
  if (t == 0) { carry_s = 0; row_start[0] = 0; }
  __syncthreads();
  for (int base = 0; base < n; base += 1024) {
    int v = (base + t < n) ? cnt[base + t] : 0;
    buf[t] = v;
    __syncthreads();
    for (int off = 1; off < 1024; off <<= 1) {
      int add = (t >= off) ? buf[t - off] : 0;
      __syncthreads();
      buf[t] += add;
      __syncthreads();
    }
    if (base + t < n) row_start[base + t + 1] = buf[t] + carry_s;
    __syncthreads();
    if (t == 0) carry_s += buf[1023];
    __syncthreads();
  }
}

__global__ void scatter_kernel(const int* __restrict__ indices, const int* __restrict__ row_start,
                               int* __restrict__ cursor, int2* __restrict__ edge_list, int E) {
  int e = blockIdx.x * blockDim.x + threadIdx.x;
  if (e >= E) return;
  int bi = indices[(size_t)e * 32];
  int bj = indices[(size_t)e * 32 + 1];
  int r = bi >> 2, c = bj >> 2;
  int pos = atomicAdd(&cursor[r], 1);
  edge_list[row_start[r] + pos] = make_int2(c, e);
}

__global__ void reorder_kernel(const int2* __restrict__ edge_list, const float* __restrict__ vals,
                               _Float16* __restrict__ vals_h, int* __restrict__ col_sorted, int E) {
  int tid = blockIdx.x * blockDim.x + threadIdx.x;
  int p = tid >> 4;
  int i = tid & 15;
  if (p >= E) return;
  int2 ce = edge_list[p];
  vals_h[(size_t)p * 16 + i] = (_Float16)vals[(size_t)ce.y * 16 + i];
  if (i == 0) col_sorted[p] = ce.x;
}

// x[b][4c+k] (fp32) -> xh[((c*batch)+b)*4 + k] (fp16 packed per node)
__global__ void pack_fp16_kernel(const float* __restrict__ in, uint2* __restrict__ out,
                                 int batch, int size) {
  __shared__ float tile[64][65];
  int c0 = blockIdx.x * 64;
  int b0 = blockIdx.y * 64;
  int tx = threadIdx.x & 63, ty = threadIdx.x >> 6;
#pragma unroll
  for (int k = 0; k < 64; k += 4) {
    int b = b0 + ty + k, c = c0 + tx;
    if (b < batch && c < size) tile[ty + k][tx] = in[(size_t)b * size + c];
  }
  __syncthreads();
#pragma unroll
  for (int it = 0; it < 4; ++it) {
    int idx = it * 256 + threadIdx.x;
    int cn_local = idx >> 6;
    int bl = idx & 63;
    int c_node = (c0 >> 2) + cn_local;
    int b = b0 + bl;
    if (b < batch && (c_node * 4 + 3) < size) {
      union { _Float16 h[4]; uint2 u; } cv;
      cv.h[0] = (_Float16)tile[bl][cn_local * 4 + 0];
      cv.h[1] = (_Float16)tile[bl][cn_local * 4 + 1];
      cv.h[2] = (_Float16)tile[bl][cn_local * 4 + 2];
      cv.h[3] = (_Float16)tile[bl][cn_local * 4 + 3];
      out[(size_t)c_node * batch + b] = cv.u;
    }
  }
}

__device__ __forceinline__ void edge_acc(const _Float16* __restrict__ vh, size_t p,
                                         uint2 xu, float* __restrict__ acc) {
  uint4 a = *(const uint4*)(vh + p * 16);
  uint4 c = *(const uint4*)(vh + p * 16 + 8);
  h2_t x01 = as_h2(xu.x), x23 = as_h2(xu.y);
  acc[0] = fdot2(as_h2(a.x), x01, acc[0]);
  acc[0] = fdot2(as_h2(a.y), x23, acc[0]);
  acc[1] = fdot2(as_h2(a.z), x01, acc[1]);
  acc[1] = fdot2(as_h2(a.w), x23, acc[1]);
  acc[2] = fdot2(as_h2(c.x), x01, acc[2]);
  acc[2] = fdot2(as_h2(c.y), x23, acc[2]);
  acc[3] = fdot2(as_h2(c.z), x01, acc[3]);
  acc[3] = fdot2(as_h2(c.w), x23, acc[3]);
}

// Per-XCD queued spmm. nq queues; queue q owns windows {q, q+nq, ...}
// (wpq windows), npq = wpq*nqb tasks. Task t of queue q: window = q + nq*(t/nqb),
// quad-block qb = t%nqb. Block = 4 waves; wave i handles quad qb*4+i, all waves
// share the window (64 batch lanes).
__global__ __launch_bounds__(256) void spmm_kernel(
    const int* __restrict__ row_start, const int* __restrict__ col_sorted,
    const _Float16* __restrict__ vals_h, const uint2* __restrict__ xh,
    const float* __restrict__ biases, float* __restrict__ out,
    int n_nodes, int batch, int size,
    int* __restrict__ qcnt, int nq, int nqb, int npq) {
  __shared__ int task_s;
  int xcd = get_xcd() % nq;
  int wave = threadIdx.x >> 6;
  int lane = threadIdx.x & 63;

  for (int dq = 0; dq < nq; ++dq) {
    int qq = (xcd + dq) % nq;
    while (true) {
      if (threadIdx.x == 0) task_s = atomicAdd(&qcnt[qq], 1);
      __syncthreads();
      int t = task_s;
      __syncthreads();
      if (t >= npq) break;

      int w = qq + nq * (t / nqb);
      int qb = t - (t / nqb) * nqb;
      int quad = qb * 4 + wave;
      int b = w * 64 + lane;
      if (quad * 4 < n_nodes && b < batch) {
        const uint2* __restrict__ xb = xh + b;
        float acc[4][4];
#pragma unroll
        for (int i = 0; i < 16; ++i) ((float*)acc)[i] = 0.f;

#pragma unroll
        for (int rr = 0; rr < 4; ++rr) {
          int r = quad * 4 + rr;
          if (r >= n_nodes) break;
          int s = __builtin_amdgcn_readfirstlane(row_start[r]);
          int e = __builtin_amdgcn_readfirstlane(row_start[r + 1]);
          int p = s;
          for (; p + 3 < e; p += 4) {
            int c0 = col_sorted[p];
            int c1 = col_sorted[p + 1];
            int c2 = col_sorted[p + 2];
            int c3 = col_sorted[p + 3];
            uint2 x0 = xb[(size_t)c0 * batch];
            uint2 x1 = xb[(size_t)c1 * batch];
            uint2 x2 = xb[(size_t)c2 * batch];
            uint2 x3 = xb[(size_t)c3 * batch];
            edge_acc(vals_h, (size_t)p,     x0, acc[rr]);
            edge_acc(vals_h, (size_t)p + 1, x1, acc[rr]);
            edge_acc(vals_h, (size_t)p + 2, x2, acc[rr]);
            edge_acc(vals_h, (size_t)p + 3, x3, acc[rr]);
          }
          for (; p < e; ++p) {
            int c = col_sorted[p];
            uint2 xu = xb[(size_t)c * batch];
            edge_acc(vals_h, (size_t)p, xu, acc[rr]);
          }
        }

#pragma unroll
        for (int rr = 0; rr < 4; ++rr) {
          int r = quad * 4 + rr;
          if (r >= n_nodes) break;
          float4 bias = *(const float4*)&biases[r << 2];
          float4 o = make_float4(acc[rr][0] + bias.x, acc[rr][1] + bias.y,
                                 acc[rr][2] + bias.z, acc[rr][3] + bias.w);
          *(float4*)&out[(size_t)b * size + (r << 2)] = o;
        }
      }
    }
  }
}

// Fallback when ws can't hold xh: gather fp32 x directly, fp16 V.
__global__ __launch_bounds__(256) void spmm_fb_kernel(
    const int* __restrict__ row_start, const int* __restrict__ col_sorted,
    const _Float16* __restrict__ vals_h, const float* __restrict__ x,
    const float* __restrict__ biases, float* __restrict__ out,
    int n_nodes, int batch, int size) {
  int quad = blockIdx.x;
  int b = blockIdx.y * blockDim.x + threadIdx.x;
  if (b >= batch || quad * 4 >= n_nodes) return;
  float acc[4][4];
#pragma unroll
  for (int i = 0; i < 16; ++i) ((float*)acc)[i] = 0.f;
#pragma unroll
  for (int rr = 0; rr < 4; ++rr) {
    int r = quad * 4 + rr;
    if (r >= n_nodes) break;
    int s = row_start[r], e = row_start[r + 1];
    for (int p = s; p < e; ++p) {
      int c = col_sorted[p];
      float4 xv = *(const float4*)&x[(size_t)b * size + (c << 2)];
      const _Float16* V = vals_h + (size_t)p * 16;
#pragma unroll
      for (int i = 0; i < 4; ++i) {
        acc[rr][i] += (float)V[i * 4 + 0] * xv.x + (float)V[i * 4 + 1] * xv.y +
                      (float)V[i * 4 + 2] * xv.z + (float)V[i * 4 + 3] * xv.w;
      }
    }
  }
#pragma unroll
  for (int rr = 0; rr < 4; ++rr) {
    int r = quad * 4 + rr;
    if (r >= n_nodes) break;
    float4 bias = *(const float4*)&biases[r << 2];
    float4 o = make_float4(acc[rr][0] + bias.x, acc[rr][1] + bias.y,
                           acc[rr][2] + bias.z, acc[rr][3] + bias.w);
    *(float4*)&out[(size_t)b * size + (r << 2)] = o;
  }
}

// Last-resort fallback (tiny ws)
__global__ void bias_init_kernel(float* __restrict__ out, const float* __restrict__ biases,
                                 int batch, int size) {
  size_t t = (size_t)blockIdx.x * blockDim.x + threadIdx.x;
  size_t total = (size_t)batch * size;
  if (t >= total) return;
  out[t] = biases[t % size];
}

__global__ void atomic_spmm_kernel(const int* __restrict__ indices, const float* __restrict__ vals,
                                   const float* __restrict__ x, float* __restrict__ out,
                                   int nnz, int batch, int size) {
  int n = blockIdx.x;
  if (n >= nnz) return;
  int i = indices[(size_t)n * 2];
  int j = indices[(size_t)n * 2 + 1];
  float v = vals[n];
  for (int b = threadIdx.x; b < batch; b += blockDim.x) {
    atomicAdd(&out[(size_t)b * size + i], v * x[(size_t)b * size + j]);
  }
}

extern "C" void kernel_launch(void* const* d_in, const int* in_sizes, int n_in,
                              void* d_out, int out_size, void* d_ws, size_t ws_size,
                              hipStream_t stream) {
  const float* x       = (const float*)d_in[0];
  const float* values  = (const float*)d_in[1];
  const float* biases  = (const float*)d_in[2];
  const int*   indices = (const int*)d_in[3];
  float* out = (float*)d_out;

  const int size    = in_sizes[2];        // 40000
  const int nnz     = in_sizes[1];        // 5,120,000
  const int batch   = in_sizes[0] / size; // 1024
  const int E       = nnz / 16;           // 320,000
  const int n_nodes = size / 4;           // 10,000

  // ---- workspace layout ----
  char* ws = (char*)d_ws;
  size_t off = 0;
  int* cnt = (int*)(ws + off);        off += (size_t)n_nodes * 4;
  int* cursor = (int*)(ws + off);     off += (size_t)n_nodes * 4;
  int* qcnt = (int*)(ws + off);       off += 8 * 4;
  int* row_start = (int*)(ws + off);  off += ((size_t)n_nodes + 1) * 4;
  off = (off + 255) & ~(size_t)255;
  int* partial = (int*)(ws + off);    off += 64 * 4;
  int* offs = (int*)(ws + off);       off += 64 * 4;
  off = (off + 255) & ~(size_t)255;
  int* col_sorted = (int*)(ws + off); off += (size_t)E * 4;
  off = (off + 255) & ~(size_t)255;
  int2* edge_list = (int2*)(ws + off); off += (size_t)E * 8;
  off = (off + 255) & ~(size_t)255;
  _Float16* vals_h = (_Float16*)(ws + off); off += (size_t)E * 32;
  off = (off + 255) & ~(size_t)255;
  size_t need_csr = off;
  uint2* xh = (uint2*)(ws + off);
  off += (size_t)(size / 4) * batch * 8;
  size_t need_full = off;

  const int n_quads = (n_nodes + 3) / 4;

  if (ws_size >= need_csr) {
    // zeroes cnt, cursor, qcnt (contiguous)
    hipMemsetAsync(cnt, 0, ((size_t)2 * n_nodes + 8) * 4, stream);
    hist_kernel<<<(E + 255) / 256, 256, 0, stream>>>(indices, cnt, E);

    int nb = (n_nodes + 255) / 256;
    if (nb <= 64) {
      scan_reduce_kernel<<<nb, 256, 0, stream>>>(cnt, partial, n_nodes);
      scan_mid_kernel<<<1, 64, 0, stream>>>(partial, offs, nb);
      scan_final_kernel<<<nb, 256, 0, stream>>>(cnt, offs, row_start, n_nodes);
    } else {
      scan_kernel<<<1, 1024, 0, stream>>>(cnt, row_start, n_nodes);
    }

    scatter_kernel<<<(E + 255) / 256, 256, 0, stream>>>(indices, row_start, cursor, edge_list, E);
    reorder_kernel<<<((size_t)E * 16 + 255) / 256, 256, 0, stream>>>(edge_list, values, vals_h, col_sorted, E);

    if (ws_size >= need_full) {
      pack_fp16_kernel<<<dim3((size + 63) / 64, (batch + 63) / 64), 256, 0, stream>>>(
          x, xh, batch, size);
      int nqb = (n_quads + 3) / 4;          // quad-blocks of 4 quads (1 per wave)
      int nwin = (batch + 63) / 64;         // 64-lane batch windows
      int nq = ((nwin & 7) == 0) ? 8 : 1;   // per-XCD queues if evenly divisible
      int wpq = nwin / nq;                  // windows per queue
      int npq = wpq * nqb;                  // tasks per queue
      int total_tasks = nq * npq;
      int gridx = total_tasks < 2048 ? total_tasks : 2048;
      spmm_kernel<<<gridx, 256, 0, stream>>>(row_start, col_sorted, vals_h, xh,
                                             biases, out, n_nodes, batch, size,
                                             qcnt, nq, nqb, npq);
    } else {
      dim3 grid(n_quads, (batch + 255) / 256);
      spmm_fb_kernel<<<grid, 256, 0, stream>>>(row_start, col_sorted, vals_h, x,
                                               biases, out, n_nodes, batch, size);
    }
  } else {
    size_t total = (size_t)batch * size;
    bias_init_kernel<<<(total + 255) / 256, 256, 0, stream>>>(out, biases, batch, size);
    atomic_spmm_kernel<<<nnz, 256, 0, stream>>>(indices, values, x, out, nnz, batch, size);
  }
}

// Round 7
// 483.453 us; speedup vs baseline: 1.2843x; 1.2843x over previous
//
#include <hip/hip_runtime.h>

// y[b, i] = sum v * x[b, j] + biases[i]
// 320k edges, each a dense 4x4 block at (4r, 4c); values row-major per edge.
// Round 7: round-3 structure (slot-minor window interleave, wave-uniform rows,
// readfirstlane bounds, L2-merged full-line stores) + 2 batch elems per lane
// (uint4 gathers, half the issue count) + slimmed prepass (single indices
// pass, compact rc array, direct col/perm scatter).

typedef _Float16 h2_t __attribute__((ext_vector_type(2)));

__device__ __forceinline__ h2_t as_h2(unsigned u) {
  union { unsigned u; h2_t h; } v; v.u = u; return v.h;
}

__device__ __forceinline__ float fdot2(h2_t a, h2_t b, float c) {
#if __has_builtin(__builtin_amdgcn_fdot2)
  return __builtin_amdgcn_fdot2(a, b, c, false);
#else
  return c + (float)a.x * (float)b.x + (float)a.y * (float)b.y;
#endif
}

// k1: decode indices once; histogram + compact (r,c) array
__global__ void hist_rc_kernel(const int* __restrict__ indices, int* __restrict__ cnt,
                               int2* __restrict__ rc, int E) {
  int e = blockIdx.x * blockDim.x + threadIdx.x;
  if (e >= E) return;
  int bi = indices[(size_t)e * 32];
  int bj = indices[(size_t)e * 32 + 1];
  int r = bi >> 2, c = bj >> 2;
  rc[e] = make_int2(r, c);
  atomicAdd(&cnt[r], 1);
}

// ---- parallel scan: reduce -> wave-scan of partials -> final ----
__global__ void scan_reduce_kernel(const int* __restrict__ cnt, int* __restrict__ partial, int n) {
  __shared__ int sh[256];
  int i = blockIdx.x * 256 + threadIdx.x;
  sh[threadIdx.x] = (i < n) ? cnt[i] : 0;
  __syncthreads();
  for (int off = 128; off > 0; off >>= 1) {
    if (threadIdx.x < off) sh[threadIdx.x] += sh[threadIdx.x + off];
    __syncthreads();
  }
  if (threadIdx.x == 0) partial[blockIdx.x] = sh[0];
}

__global__ void scan_mid_kernel(const int* __restrict__ partial, int* __restrict__ offs, int nb) {
  int t = threadIdx.x;
  int v = (t < nb) ? partial[t] : 0;
  for (int d = 1; d < 64; d <<= 1) {
    int u = __shfl_up(v, d);
    if (t >= d) v += u;
  }
  if (t < nb) offs[t] = v;  // inclusive
}

__global__ void scan_final_kernel(const int* __restrict__ cnt, const int* __restrict__ offs,
                                  int* __restrict__ row_start, int n) {
  __shared__ int sh[256];
  int blk = blockIdx.x;
  int i = blk * 256 + threadIdx.x;
  int v = (i < n) ? cnt[i] : 0;
  sh[threadIdx.x] = v;
  __syncthreads();
  for (int off = 1; off < 256; off <<= 1) {
    int add = (threadIdx.x >= off) ? sh[threadIdx.x - off] : 0;
    __syncthreads();
    sh[threadIdx.x] += add;
    __syncthreads();
  }
  int base = (blk == 0) ? 0 : offs[blk - 1];
  if (i < n) row_start[i + 1] = sh[threadIdx.x] + base;
  if (blk == 0 && threadIdx.x == 0) row_start[0] = 0;
}

__global__ void scan_kernel(const int* __restrict__ cnt, int* __restrict__ row_start, int n) {
  __shared__ int buf[1024];
  __shared__ int carry_s;
  int t = threadIdx.x;
  if (t == 0) { carry_s = 0; row_start[0] = 0; }
  __syncthreads();
  for (int base = 0; base < n; base += 1024) {
    int v = (base + t < n) ? cnt[base + t] : 0;
    buf[t] = v;
    __syncthreads();
    for (int off = 1; off < 1024; off <<= 1) {
      int add = (t >= off) ? buf[t - off] : 0;
      __syncthreads();
      buf[t] += add;
      __syncthreads();
    }
    if (base + t < n) row_start[base + t + 1] = buf[t] + carry_s;
    __syncthreads();
    if (t == 0) carry_s += buf[1023];
    __syncthreads();
  }
}

// k2: scatter from compact rc -> col_sorted + perm (CSR order)
__global__ void scatter_kernel(const int2* __restrict__ rc, const int* __restrict__ row_start,
                               int* __restrict__ cursor, int* __restrict__ col_sorted,
                               int* __restrict__ perm, int E) {
  int e = blockIdx.x * blockDim.x + threadIdx.x;
  if (e >= E) return;
  int2 v = rc[e];
  int pos = row_start[v.x] + atomicAdd(&cursor[v.x], 1);
  col_sorted[pos] = v.y;
  perm[pos] = e;
}

// k3: vals (fp32, edge-major) -> vals_h (fp16, CSR order) via perm
__global__ void reorder_kernel(const int* __restrict__ perm, const float* __restrict__ vals,
                               _Float16* __restrict__ vals_h, int E) {
  int tid = blockIdx.x * blockDim.x + threadIdx.x;
  int p = tid >> 4;
  int i = tid & 15;
  if (p >= E) return;
  vals_h[(size_t)p * 16 + i] = (_Float16)vals[(size_t)perm[p] * 16 + i];
}

// x[b][4c+k] (fp32) -> xh[((c*batch)+b)*4 + k] (fp16 packed per node)
__global__ void pack_fp16_kernel(const float* __restrict__ in, uint2* __restrict__ out,
                                 int batch, int size) {
  __shared__ float tile[64][65];
  int c0 = blockIdx.x * 64;
  int b0 = blockIdx.y * 64;
  int tx = threadIdx.x & 63, ty = threadIdx.x >> 6;
#pragma unroll
  for (int k = 0; k < 64; k += 4) {
    int b = b0 + ty + k, c = c0 + tx;
    if (b < batch && c < size) tile[ty + k][tx] = in[(size_t)b * size + c];
  }
  __syncthreads();
#pragma unroll
  for (int it = 0; it < 4; ++it) {
    int idx = it * 256 + threadIdx.x;
    int cn_local = idx >> 6;
    int bl = idx & 63;
    int c_node = (c0 >> 2) + cn_local;
    int b = b0 + bl;
    if (b < batch && (c_node * 4 + 3) < size) {
      union { _Float16 h[4]; uint2 u; } cv;
      cv.h[0] = (_Float16)tile[bl][cn_local * 4 + 0];
      cv.h[1] = (_Float16)tile[bl][cn_local * 4 + 1];
      cv.h[2] = (_Float16)tile[bl][cn_local * 4 + 2];
      cv.h[3] = (_Float16)tile[bl][cn_local * 4 + 3];
      out[(size_t)c_node * batch + b] = cv.u;
    }
  }
}

// One edge, two batch elements (X = 4 fp16 of b0, then 4 fp16 of b1).
__device__ __forceinline__ void edge_acc2(const _Float16* __restrict__ vh, size_t p,
                                          uint4 X, float* __restrict__ a0,
                                          float* __restrict__ a1) {
  uint4 A = *(const uint4*)(vh + p * 16);      // rows 0,1 of V
  uint4 C = *(const uint4*)(vh + p * 16 + 8);  // rows 2,3 of V
  h2_t x01a = as_h2(X.x), x23a = as_h2(X.y);
  h2_t x01b = as_h2(X.z), x23b = as_h2(X.w);
  a0[0] = fdot2(as_h2(A.x), x01a, a0[0]); a0[0] = fdot2(as_h2(A.y), x23a, a0[0]);
  a0[1] = fdot2(as_h2(A.z), x01a, a0[1]); a0[1] = fdot2(as_h2(A.w), x23a, a0[1]);
  a0[2] = fdot2(as_h2(C.x), x01a, a0[2]); a0[2] = fdot2(as_h2(C.y), x23a, a0[2]);
  a0[3] = fdot2(as_h2(C.z), x01a, a0[3]); a0[3] = fdot2(as_h2(C.w), x23a, a0[3]);
  a1[0] = fdot2(as_h2(A.x), x01b, a1[0]); a1[0] = fdot2(as_h2(A.y), x23b, a1[0]);
  a1[1] = fdot2(as_h2(A.z), x01b, a1[1]); a1[1] = fdot2(as_h2(A.w), x23b, a1[1]);
  a1[2] = fdot2(as_h2(C.x), x01b, a1[2]); a1[2] = fdot2(as_h2(C.y), x23b, a1[2]);
  a1[3] = fdot2(as_h2(C.z), x01b, a1[3]); a1[3] = fdot2(as_h2(C.w), x23b, a1[3]);
}

// spmm: block = 4 waves, each wave owns one quad (4 block-rows); all waves
// share one 128-batch window (2 batch elems / lane via uint4). Slot-minor
// grid: consecutive blocks = same rows, all windows (best measured FETCH).
__global__ __launch_bounds__(256) void spmm_kernel(
    const int* __restrict__ row_start, const int* __restrict__ col_sorted,
    const _Float16* __restrict__ vals_h, const uint4* __restrict__ xh4,
    const float* __restrict__ biases, float* __restrict__ out,
    int n_nodes, int batch, int size, int nwin) {
  int bx = blockIdx.x;
  int w = bx % nwin;
  int qg = bx / nwin;
  int wave = threadIdx.x >> 6;
  int lane = threadIdx.x & 63;
  int quad = qg * 4 + wave;
  if (quad * 4 >= n_nodes) return;
  int bhalf = batch >> 1;  // batch pairs
  int bh = w * 64 + lane;
  bool bvalid = (bh < bhalf);
  int bhc = bvalid ? bh : bhalf - 1;
  const uint4* __restrict__ xb = xh4 + bhc;

  float acc[4][2][4];
#pragma unroll
  for (int i = 0; i < 32; ++i) ((float*)acc)[i] = 0.f;

#pragma unroll
  for (int rr = 0; rr < 4; ++rr) {
    int r = quad * 4 + rr;
    if (r >= n_nodes) break;
    int s = __builtin_amdgcn_readfirstlane(row_start[r]);
    int e = __builtin_amdgcn_readfirstlane(row_start[r + 1]);
    int p = s;
    for (; p + 3 < e; p += 4) {
      int c0 = col_sorted[p];
      int c1 = col_sorted[p + 1];
      int c2 = col_sorted[p + 2];
      int c3 = col_sorted[p + 3];
      uint4 X0 = xb[(size_t)c0 * bhalf];
      uint4 X1 = xb[(size_t)c1 * bhalf];
      uint4 X2 = xb[(size_t)c2 * bhalf];
      uint4 X3 = xb[(size_t)c3 * bhalf];
      edge_acc2(vals_h, (size_t)p,     X0, acc[rr][0], acc[rr][1]);
      edge_acc2(vals_h, (size_t)p + 1, X1, acc[rr][0], acc[rr][1]);
      edge_acc2(vals_h, (size_t)p + 2, X2, acc[rr][0], acc[rr][1]);
      edge_acc2(vals_h, (size_t)p + 3, X3, acc[rr][0], acc[rr][1]);
    }
    for (; p < e; ++p) {
      int c = col_sorted[p];
      uint4 X = xb[(size_t)c * bhalf];
      edge_acc2(vals_h, (size_t)p, X, acc[rr][0], acc[rr][1]);
    }
  }

  if (bvalid) {
#pragma unroll
    for (int j = 0; j < 2; ++j) {
      size_t b = (size_t)bh * 2 + j;
#pragma unroll
      for (int rr = 0; rr < 4; ++rr) {
        int r = quad * 4 + rr;
        if (r >= n_nodes) break;
        float4 bias = *(const float4*)&biases[r << 2];
        float4 o = make_float4(acc[rr][j][0] + bias.x, acc[rr][j][1] + bias.y,
                               acc[rr][j][2] + bias.z, acc[rr][j][3] + bias.w);
        *(float4*)&out[b * size + (r << 2)] = o;
      }
    }
  }
}

// Fallback when ws can't hold xh: gather fp32 x directly, fp16 V.
__global__ __launch_bounds__(256) void spmm_fb_kernel(
    const int* __restrict__ row_start, const int* __restrict__ col_sorted,
    const _Float16* __restrict__ vals_h, const float* __restrict__ x,
    const float* __restrict__ biases, float* __restrict__ out,
    int n_nodes, int batch, int size) {
  int quad = blockIdx.x;
  int b = blockIdx.y * blockDim.x + threadIdx.x;
  if (b >= batch || quad * 4 >= n_nodes) return;
  float acc[4][4];
#pragma unroll
  for (int i = 0; i < 16; ++i) ((float*)acc)[i] = 0.f;
#pragma unroll
  for (int rr = 0; rr < 4; ++rr) {
    int r = quad * 4 + rr;
    if (r >= n_nodes) break;
    int s = row_start[r], e = row_start[r + 1];
    for (int p = s; p < e; ++p) {
      int c = col_sorted[p];
      float4 xv = *(const float4*)&x[(size_t)b * size + (c << 2)];
      const _Float16* V = vals_h + (size_t)p * 16;
#pragma unroll
      for (int i = 0; i < 4; ++i) {
        acc[rr][i] += (float)V[i * 4 + 0] * xv.x + (float)V[i * 4 + 1] * xv.y +
                      (float)V[i * 4 + 2] * xv.z + (float)V[i * 4 + 3] * xv.w;
      }
    }
  }
#pragma unroll
  for (int rr = 0; rr < 4; ++rr) {
    int r = quad * 4 + rr;
    if (r >= n_nodes) break;
    float4 bias = *(const float4*)&biases[r << 2];
    float4 o = make_float4(acc[rr][0] + bias.x, acc[rr][1] + bias.y,
                           acc[rr][2] + bias.z, acc[rr][3] + bias.w);
    *(float4*)&out[(size_t)b * size + (r << 2)] = o;
  }
}

// Last-resort fallback (tiny ws)
__global__ void bias_init_kernel(float* __restrict__ out, const float* __restrict__ biases,
                                 int batch, int size) {
  size_t t = (size_t)blockIdx.x * blockDim.x + threadIdx.x;
  size_t total = (size_t)batch * size;
  if (t >= total) return;
  out[t] = biases[t % size];
}

__global__ void atomic_spmm_kernel(const int* __restrict__ indices, const float* __restrict__ vals,
                                   const float* __restrict__ x, float* __restrict__ out,
                                   int nnz, int batch, int size) {
  int n = blockIdx.x;
  if (n >= nnz) return;
  int i = indices[(size_t)n * 2];
  int j = indices[(size_t)n * 2 + 1];
  float v = vals[n];
  for (int b = threadIdx.x; b < batch; b += blockDim.x) {
    atomicAdd(&out[(size_t)b * size + i], v * x[(size_t)b * size + j]);
  }
}

extern "C" void kernel_launch(void* const* d_in, const int* in_sizes, int n_in,
                              void* d_out, int out_size, void* d_ws, size_t ws_size,
                              hipStream_t stream) {
  const float* x       = (const float*)d_in[0];
  const float* values  = (const float*)d_in[1];
  const float* biases  = (const float*)d_in[2];
  const int*   indices = (const int*)d_in[3];
  float* out = (float*)d_out;

  const int size    = in_sizes[2];        // 40000
  const int nnz     = in_sizes[1];        // 5,120,000
  const int batch   = in_sizes[0] / size; // 1024
  const int E       = nnz / 16;           // 320,000
  const int n_nodes = size / 4;           // 10,000

  // ---- workspace layout ----
  char* ws = (char*)d_ws;
  size_t off = 0;
  int* cnt = (int*)(ws + off);        off += (size_t)n_nodes * 4;
  int* cursor = (int*)(ws + off);     off += (size_t)n_nodes * 4;
  int* row_start = (int*)(ws + off);  off += ((size_t)n_nodes + 1) * 4;
  off = (off + 255) & ~(size_t)255;
  int* partial = (int*)(ws + off);    off += 64 * 4;
  int* offs = (int*)(ws + off);       off += 64 * 4;
  off = (off + 255) & ~(size_t)255;
  int* col_sorted = (int*)(ws + off); off += (size_t)E * 4;
  off = (off + 255) & ~(size_t)255;
  int* perm = (int*)(ws + off);       off += (size_t)E * 4;
  off = (off + 255) & ~(size_t)255;
  int2* rc = (int2*)(ws + off);       off += (size_t)E * 8;
  off = (off + 255) & ~(size_t)255;
  _Float16* vals_h = (_Float16*)(ws + off); off += (size_t)E * 32;
  off = (off + 255) & ~(size_t)255;
  size_t need_csr = off;
  uint2* xh = (uint2*)(ws + off);
  off += (size_t)(size / 4) * batch * 8;
  size_t need_full = off;

  const int n_quads = (n_nodes + 3) / 4;

  if (ws_size >= need_csr) {
    hipMemsetAsync(cnt, 0, (size_t)2 * n_nodes * 4, stream);  // cnt + cursor
    hist_rc_kernel<<<(E + 255) / 256, 256, 0, stream>>>(indices, cnt, rc, E);

    int nb = (n_nodes + 255) / 256;
    if (nb <= 64) {
      scan_reduce_kernel<<<nb, 256, 0, stream>>>(cnt, partial, n_nodes);
      scan_mid_kernel<<<1, 64, 0, stream>>>(partial, offs, nb);
      scan_final_kernel<<<nb, 256, 0, stream>>>(cnt, offs, row_start, n_nodes);
    } else {
      scan_kernel<<<1, 1024, 0, stream>>>(cnt, row_start, n_nodes);
    }

    scatter_kernel<<<(E + 255) / 256, 256, 0, stream>>>(rc, row_start, cursor,
                                                        col_sorted, perm, E);
    reorder_kernel<<<((size_t)E * 16 + 255) / 256, 256, 0, stream>>>(perm, values, vals_h, E);

    if (ws_size >= need_full && (batch & 1) == 0) {
      pack_fp16_kernel<<<dim3((size + 63) / 64, (batch + 63) / 64), 256, 0, stream>>>(
          x, xh, batch, size);
      int nqg = (n_quads + 3) / 4;          // quad-groups of 4 (1 per wave)
      int nwin = (batch / 2 + 63) / 64;     // 128-batch windows (64 pairs)
      spmm_kernel<<<nqg * nwin, 256, 0, stream>>>(row_start, col_sorted, vals_h,
                                                  (const uint4*)xh, biases, out,
                                                  n_nodes, batch, size, nwin);
    } else {
      dim3 grid(n_quads, (batch + 255) / 256);
      spmm_fb_kernel<<<grid, 256, 0, stream>>>(row_start, col_sorted, vals_h, x,
                                               biases, out, n_nodes, batch, size);
    }
  } else {
    size_t total = (size_t)batch * size;
    bias_init_kernel<<<(total + 255) / 256, 256, 0, stream>>>(out, biases, batch, size);
    atomic_spmm_kernel<<<nnz, 256, 0, stream>>>(indices, values, x, out, nnz, batch, size);
  }
}

// Round 8
// 400.627 us; speedup vs baseline: 1.5498x; 1.2067x over previous
//
#include <hip/hip_runtime.h>

// y[b, i] = sum v * x[b, j] + biases[i]
// 320k edges, each a dense 4x4 block at (4r, 4c); values row-major per edge.
// Round 8: round-7 main loop unchanged. Epilogue rebuilt: LDS transpose ->
// full-cache-line (256B contiguous per 16 lanes) nontemporal stores. Kills
// write amplification (334->164 MB) AND write-allocate churn through L3,
// which is the prime suspect for the 12x gather re-fetch.

typedef _Float16 h2_t __attribute__((ext_vector_type(2)));
typedef float f4_t __attribute__((ext_vector_type(4)));

__device__ __forceinline__ h2_t as_h2(unsigned u) {
  union { unsigned u; h2_t h; } v; v.u = u; return v.h;
}

__device__ __forceinline__ float fdot2(h2_t a, h2_t b, float c) {
#if __has_builtin(__builtin_amdgcn_fdot2)
  return __builtin_amdgcn_fdot2(a, b, c, false);
#else
  return c + (float)a.x * (float)b.x + (float)a.y * (float)b.y;
#endif
}

// k1: decode indices once; histogram + compact (r,c) array
__global__ void hist_rc_kernel(const int* __restrict__ indices, int* __restrict__ cnt,
                               int2* __restrict__ rc, int E) {
  int e = blockIdx.x * blockDim.x + threadIdx.x;
  if (e >= E) return;
  int bi = indices[(size_t)e * 32];
  int bj = indices[(size_t)e * 32 + 1];
  int r = bi >> 2, c = bj >> 2;
  rc[e] = make_int2(r, c);
  atomicAdd(&cnt[r], 1);
}

// ---- parallel scan: reduce -> wave-scan of partials -> final ----
__global__ void scan_reduce_kernel(const int* __restrict__ cnt, int* __restrict__ partial, int n) {
  __shared__ int sh[256];
  int i = blockIdx.x * 256 + threadIdx.x;
  sh[threadIdx.x] = (i < n) ? cnt[i] : 0;
  __syncthreads();
  for (int off = 128; off > 0; off >>= 1) {
    if (threadIdx.x < off) sh[threadIdx.x] += sh[threadIdx.x + off];
    __syncthreads();
  }
  if (threadIdx.x == 0) partial[blockIdx.x] = sh[0];
}

__global__ void scan_mid_kernel(const int* __restrict__ partial, int* __restrict__ offs, int nb) {
  int t = threadIdx.x;
  int v = (t < nb) ? partial[t] : 0;
  for (int d = 1; d < 64; d <<= 1) {
    int u = __shfl_up(v, d);
    if (t >= d) v += u;
  }
  if (t < nb) offs[t] = v;  // inclusive
}

__global__ void scan_final_kernel(const int* __restrict__ cnt, const int* __restrict__ offs,
                                  int* __restrict__ row_start, int n) {
  __shared__ int sh[256];
  int blk = blockIdx.x;
  int i = blk * 256 + threadIdx.x;
  int v = (i < n) ? cnt[i] : 0;
  sh[threadIdx.x] = v;
  __syncthreads();
  for (int off = 1; off < 256; off <<= 1) {
    int add = (threadIdx.x >= off) ? sh[threadIdx.x - off] : 0;
    __syncthreads();
    sh[threadIdx.x] += add;
    __syncthreads();
  }
  int base = (blk == 0) ? 0 : offs[blk - 1];
  if (i < n) row_start[i + 1] = sh[threadIdx.x] + base;
  if (blk == 0 && threadIdx.x == 0) row_start[0] = 0;
}

__global__ void scan_kernel(const int* __restrict__ cnt, int* __restrict__ row_start, int n) {
  __shared__ int buf[1024];
  __shared__ int carry_s;
  int t = threadIdx.x;
  if (t == 0) { carry_s = 0; row_start[0] = 0; }
  __syncthreads();
  for (int base = 0; base < n; base += 1024) {
    int v = (base + t < n) ? cnt[base + t] : 0;
    buf[t] = v;
    __syncthreads();
    for (int off = 1; off < 1024; off <<= 1) {
      int add = (t >= off) ? buf[t - off] : 0;
      __syncthreads();
      buf[t] += add;
      __syncthreads();
    }
    if (base + t < n) row_start[base + t + 1] = buf[t] + carry_s;
    __syncthreads();
    if (t == 0) carry_s += buf[1023];
    __syncthreads();
  }
}

// k2: scatter from compact rc -> col_sorted + perm (CSR order)
__global__ void scatter_kernel(const int2* __restrict__ rc, const int* __restrict__ row_start,
                               int* __restrict__ cursor, int* __restrict__ col_sorted,
                               int* __restrict__ perm, int E) {
  int e = blockIdx.x * blockDim.x + threadIdx.x;
  if (e >= E) return;
  int2 v = rc[e];
  int pos = row_start[v.x] + atomicAdd(&cursor[v.x], 1);
  col_sorted[pos] = v.y;
  perm[pos] = e;
}

// k3: vals (fp32, edge-major) -> vals_h (fp16, CSR order) via perm
__global__ void reorder_kernel(const int* __restrict__ perm, const float* __restrict__ vals,
                               _Float16* __restrict__ vals_h, int E) {
  int tid = blockIdx.x * blockDim.x + threadIdx.x;
  int p = tid >> 4;
  int i = tid & 15;
  if (p >= E) return;
  vals_h[(size_t)p * 16 + i] = (_Float16)vals[(size_t)perm[p] * 16 + i];
}

// x[b][4c+k] (fp32) -> xh[((c*batch)+b)*4 + k] (fp16 packed per node)
__global__ void pack_fp16_kernel(const float* __restrict__ in, uint2* __restrict__ out,
                                 int batch, int size) {
  __shared__ float tile[64][65];
  int c0 = blockIdx.x * 64;
  int b0 = blockIdx.y * 64;
  int tx = threadIdx.x & 63, ty = threadIdx.x >> 6;
#pragma unroll
  for (int k = 0; k < 64; k += 4) {
    int b = b0 + ty + k, c = c0 + tx;
    if (b < batch && c < size) tile[ty + k][tx] = in[(size_t)b * size + c];
  }
  __syncthreads();
#pragma unroll
  for (int it = 0; it < 4; ++it) {
    int idx = it * 256 + threadIdx.x;
    int cn_local = idx >> 6;
    int bl = idx & 63;
    int c_node = (c0 >> 2) + cn_local;
    int b = b0 + bl;
    if (b < batch && (c_node * 4 + 3) < size) {
      union { _Float16 h[4]; uint2 u; } cv;
      cv.h[0] = (_Float16)tile[bl][cn_local * 4 + 0];
      cv.h[1] = (_Float16)tile[bl][cn_local * 4 + 1];
      cv.h[2] = (_Float16)tile[bl][cn_local * 4 + 2];
      cv.h[3] = (_Float16)tile[bl][cn_local * 4 + 3];
      out[(size_t)c_node * batch + b] = cv.u;
    }
  }
}

// One edge, two batch elements (X = 4 fp16 of b0, then 4 fp16 of b1).
__device__ __forceinline__ void edge_acc2(const _Float16* __restrict__ vh, size_t p,
                                          uint4 X, float* __restrict__ a0,
                                          float* __restrict__ a1) {
  uint4 A = *(const uint4*)(vh + p * 16);      // rows 0,1 of V
  uint4 C = *(const uint4*)(vh + p * 16 + 8);  // rows 2,3 of V
  h2_t x01a = as_h2(X.x), x23a = as_h2(X.y);
  h2_t x01b = as_h2(X.z), x23b = as_h2(X.w);
  a0[0] = fdot2(as_h2(A.x), x01a, a0[0]); a0[0] = fdot2(as_h2(A.y), x23a, a0[0]);
  a0[1] = fdot2(as_h2(A.z), x01a, a0[1]); a0[1] = fdot2(as_h2(A.w), x23a, a0[1]);
  a0[2] = fdot2(as_h2(C.x), x01a, a0[2]); a0[2] = fdot2(as_h2(C.y), x23a, a0[2]);
  a0[3] = fdot2(as_h2(C.z), x01a, a0[3]); a0[3] = fdot2(as_h2(C.w), x23a, a0[3]);
  a1[0] = fdot2(as_h2(A.x), x01b, a1[0]); a1[0] = fdot2(as_h2(A.y), x23b, a1[0]);
  a1[1] = fdot2(as_h2(A.z), x01b, a1[1]); a1[1] = fdot2(as_h2(A.w), x23b, a1[1]);
  a1[2] = fdot2(as_h2(C.x), x01b, a1[2]); a1[2] = fdot2(as_h2(C.y), x23b, a1[2]);
  a1[3] = fdot2(as_h2(C.z), x01b, a1[3]); a1[3] = fdot2(as_h2(C.w), x23b, a1[3]);
}

// spmm: block = 4 waves, each wave owns one quad (4 block-rows); all waves
// share one 128-batch window (2 batch elems / lane via uint4). Slot-minor
// grid. Epilogue: LDS transpose -> 256B-contiguous full-line nt stores.
__global__ __launch_bounds__(256) void spmm_kernel(
    const int* __restrict__ row_start, const int* __restrict__ col_sorted,
    const _Float16* __restrict__ vals_h, const uint4* __restrict__ xh4,
    const float* __restrict__ biases, float* __restrict__ out,
    int n_nodes, int batch, int size, int nwin) {
  __shared__ float tile[64][68];  // [batch 64][64 out floats + pad]
  int bx = blockIdx.x;
  int w = bx % nwin;
  int qg = bx / nwin;
  int wave = threadIdx.x >> 6;
  int lane = threadIdx.x & 63;
  int quad = qg * 4 + wave;
  bool qvalid = (quad * 4 < n_nodes);
  int bhalf = batch >> 1;  // batch pairs
  int bh = w * 64 + lane;
  bool bvalid = (bh < bhalf);
  int bhc = bvalid ? bh : bhalf - 1;
  const uint4* __restrict__ xb = xh4 + bhc;

  float acc[4][2][4];
#pragma unroll
  for (int i = 0; i < 32; ++i) ((float*)acc)[i] = 0.f;

  if (qvalid) {
#pragma unroll
    for (int rr = 0; rr < 4; ++rr) {
      int r = quad * 4 + rr;
      if (r >= n_nodes) break;
      int s = __builtin_amdgcn_readfirstlane(row_start[r]);
      int e = __builtin_amdgcn_readfirstlane(row_start[r + 1]);
      int p = s;
      for (; p + 3 < e; p += 4) {
        int c0 = col_sorted[p];
        int c1 = col_sorted[p + 1];
        int c2 = col_sorted[p + 2];
        int c3 = col_sorted[p + 3];
        uint4 X0 = xb[(size_t)c0 * bhalf];
        uint4 X1 = xb[(size_t)c1 * bhalf];
        uint4 X2 = xb[(size_t)c2 * bhalf];
        uint4 X3 = xb[(size_t)c3 * bhalf];
        edge_acc2(vals_h, (size_t)p,     X0, acc[rr][0], acc[rr][1]);
        edge_acc2(vals_h, (size_t)p + 1, X1, acc[rr][0], acc[rr][1]);
        edge_acc2(vals_h, (size_t)p + 2, X2, acc[rr][0], acc[rr][1]);
        edge_acc2(vals_h, (size_t)p + 3, X3, acc[rr][0], acc[rr][1]);
      }
      for (; p < e; ++p) {
        int c = col_sorted[p];
        uint4 X = xb[(size_t)c * bhalf];
        edge_acc2(vals_h, (size_t)p, X, acc[rr][0], acc[rr][1]);
      }
    }
  }

  // ---- epilogue: two phases of 64 batch elements each ----
#pragma unroll
  for (int ph = 0; ph < 2; ++ph) {
    __syncthreads();
    // stage: lanes whose batch pairs fall in this phase write acc(+bias) to LDS
    if (qvalid && bvalid && (lane >> 5) == ph) {
      int lb = lane & 31;  // local pair index within phase
#pragma unroll
      for (int rr = 0; rr < 4; ++rr) {
        int r = quad * 4 + rr;
        if (r < n_nodes) {
          float4 bias = *(const float4*)&biases[r << 2];
#pragma unroll
          for (int j = 0; j < 2; ++j) {
            float4 o = make_float4(acc[rr][j][0] + bias.x, acc[rr][j][1] + bias.y,
                                   acc[rr][j][2] + bias.z, acc[rr][j][3] + bias.w);
            *(float4*)&tile[lb * 2 + j][wave * 16 + rr * 4] = o;
          }
        }
      }
    }
    __syncthreads();
    // sweep: 64 batch x 16 chunks of 16B; 16 lanes cover 256B contiguous
    // (= 2 full 128B lines); nontemporal -> no RFO, no L2/L3 allocation.
#pragma unroll
    for (int it = 0; it < 4; ++it) {
      int idx = it * 256 + threadIdx.x;
      int bl = idx >> 4;   // 0..63
      int f4 = idx & 15;   // 16B chunk within the 64-float row group
      int r = qg * 16 + f4;          // block-row of this chunk
      int b = w * 128 + ph * 64 + bl;
      if (r < n_nodes && b < batch) {
        f4_t v = *(f4_t*)&tile[bl][f4 * 4];
        __builtin_nontemporal_store(v, (f4_t*)&out[(size_t)b * size + (size_t)r * 4]);
      }
    }
  }
}

// Fallback when ws can't hold xh: gather fp32 x directly, fp16 V.
__global__ __launch_bounds__(256) void spmm_fb_kernel(
    const int* __restrict__ row_start, const int* __restrict__ col_sorted,
    const _Float16* __restrict__ vals_h, const float* __restrict__ x,
    const float* __restrict__ biases, float* __restrict__ out,
    int n_nodes, int batch, int size) {
  int quad = blockIdx.x;
  int b = blockIdx.y * blockDim.x + threadIdx.x;
  if (b >= batch || quad * 4 >= n_nodes) return;
  float acc[4][4];
#pragma unroll
  for (int i = 0; i < 16; ++i) ((float*)acc)[i] = 0.f;
#pragma unroll
  for (int rr = 0; rr < 4; ++rr) {
    int r = quad * 4 + rr;
    if (r >= n_nodes) break;
    int s = row_start[r], e = row_start[r + 1];
    for (int p = s; p < e; ++p) {
      int c = col_sorted[p];
      float4 xv = *(const float4*)&x[(size_t)b * size + (c << 2)];
      const _Float16* V = vals_h + (size_t)p * 16;
#pragma unroll
      for (int i = 0; i < 4; ++i) {
        acc[rr][i] += (float)V[i * 4 + 0] * xv.x + (float)V[i * 4 + 1] * xv.y +
                      (float)V[i * 4 + 2] * xv.z + (float)V[i * 4 + 3] * xv.w;
      }
    }
  }
#pragma unroll
  for (int rr = 0; rr < 4; ++rr) {
    int r = quad * 4 + rr;
    if (r >= n_nodes) break;
    float4 bias = *(const float4*)&biases[r << 2];
    float4 o = make_float4(acc[rr][0] + bias.x, acc[rr][1] + bias.y,
                           acc[rr][2] + bias.z, acc[rr][3] + bias.w);
    *(float4*)&out[(size_t)b * size + (r << 2)] = o;
  }
}

// Last-resort fallback (tiny ws)
__global__ void bias_init_kernel(float* __restrict__ out, const float* __restrict__ biases,
                                 int batch, int size) {
  size_t t = (size_t)blockIdx.x * blockDim.x + threadIdx.x;
  size_t total = (size_t)batch * size;
  if (t >= total) return;
  out[t] = biases[t % size];
}

__global__ void atomic_spmm_kernel(const int* __restrict__ indices, const float* __restrict__ vals,
                                   const float* __restrict__ x, float* __restrict__ out,
                                   int nnz, int batch, int size) {
  int n = blockIdx.x;
  if (n >= nnz) return;
  int i = indices[(size_t)n * 2];
  int j = indices[(size_t)n * 2 + 1];
  float v = vals[n];
  for (int b = threadIdx.x; b < batch; b += blockDim.x) {
    atomicAdd(&out[(size_t)b * size + i], v * x[(size_t)b * size + j]);
  }
}

extern "C" void kernel_launch(void* const* d_in, const int* in_sizes, int n_in,
                              void* d_out, int out_size, void* d_ws, size_t ws_size,
                              hipStream_t stream) {
  const float* x       = (const float*)d_in[0];
  const float* values  = (const float*)d_in[1];
  const float* biases  = (const float*)d_in[2];
  const int*   indices = (const int*)d_in[3];
  float* out = (float*)d_out;

  const int size    = in_sizes[2];        // 40000
  const int nnz     = in_sizes[1];        // 5,120,000
  const int batch   = in_sizes[0] / size; // 1024
  const int E       = nnz / 16;           // 320,000
  const int n_nodes = size / 4;           // 10,000

  // ---- workspace layout ----
  char* ws = (char*)d_ws;
  size_t off = 0;
  int* cnt = (int*)(ws + off);        off += (size_t)n_nodes * 4;
  int* cursor = (int*)(ws + off);     off += (size_t)n_nodes * 4;
  int* row_start = (int*)(ws + off);  off += ((size_t)n_nodes + 1) * 4;
  off = (off + 255) & ~(size_t)255;
  int* partial = (int*)(ws + off);    off += 64 * 4;
  int* offs = (int*)(ws + off);       off += 64 * 4;
  off = (off + 255) & ~(size_t)255;
  int* col_sorted = (int*)(ws + off); off += (size_t)E * 4;
  off = (off + 255) & ~(size_t)255;
  int* perm = (int*)(ws + off);       off += (size_t)E * 4;
  off = (off + 255) & ~(size_t)255;
  int2* rc = (int2*)(ws + off);       off += (size_t)E * 8;
  off = (off + 255) & ~(size_t)255;
  _Float16* vals_h = (_Float16*)(ws + off); off += (size_t)E * 32;
  off = (off + 255) & ~(size_t)255;
  size_t need_csr = off;
  uint2* xh = (uint2*)(ws + off);
  off += (size_t)(size / 4) * batch * 8;
  size_t need_full = off;

  const int n_quads = (n_nodes + 3) / 4;

  if (ws_size >= need_csr) {
    hipMemsetAsync(cnt, 0, (size_t)2 * n_nodes * 4, stream);  // cnt + cursor
    hist_rc_kernel<<<(E + 255) / 256, 256, 0, stream>>>(indices, cnt, rc, E);

    int nb = (n_nodes + 255) / 256;
    if (nb <= 64) {
      scan_reduce_kernel<<<nb, 256, 0, stream>>>(cnt, partial, n_nodes);
      scan_mid_kernel<<<1, 64, 0, stream>>>(partial, offs, nb);
      scan_final_kernel<<<nb, 256, 0, stream>>>(cnt, offs, row_start, n_nodes);
    } else {
      scan_kernel<<<1, 1024, 0, stream>>>(cnt, row_start, n_nodes);
    }

    scatter_kernel<<<(E + 255) / 256, 256, 0, stream>>>(rc, row_start, cursor,
                                                        col_sorted, perm, E);
    reorder_kernel<<<((size_t)E * 16 + 255) / 256, 256, 0, stream>>>(perm, values, vals_h, E);

    if (ws_size >= need_full && (batch & 1) == 0) {
      pack_fp16_kernel<<<dim3((size + 63) / 64, (batch + 63) / 64), 256, 0, stream>>>(
          x, xh, batch, size);
      int nqg = (n_quads + 3) / 4;          // quad-groups of 4 (1 per wave)
      int nwin = (batch / 2 + 63) / 64;     // 128-batch windows (64 pairs)
      spmm_kernel<<<nqg * nwin, 256, 0, stream>>>(row_start, col_sorted, vals_h,
                                                  (const uint4*)xh, biases, out,
                                                  n_nodes, batch, size, nwin);
    } else {
      dim3 grid(n_quads, (batch + 255) / 256);
      spmm_fb_kernel<<<grid, 256, 0, stream>>>(row_start, col_sorted, vals_h, x,
                                               biases, out, n_nodes, batch, size);
    }
  } else {
    size_t total = (size_t)batch * size;
    bias_init_kernel<<<(total + 255) / 256, 256, 0, stream>>>(out, biases, batch, size);
    atomic_spmm_kernel<<<nnz, 256, 0, stream>>>(indices, values, x, out, nnz, batch, size);
  }
}

// Round 9
// 378.681 us; speedup vs baseline: 1.6396x; 1.0580x over previous
//
#include <hip/hip_runtime.h>

// y[b, i] = sum v * x[b, j] + biases[i]
// 320k edges, each a dense 4x4 block at (4r, 4c); values row-major per edge.
// Round 9: spmm gains a depth-2 software pipeline (8 gathers in flight via
// static A/B chunk ping-pong). Prepass: pack+hist fused into one launch,
// vals conversion fused into scatter (perm array + reorder pass dropped).

typedef _Float16 h2_t __attribute__((ext_vector_type(2)));
typedef float f4_t __attribute__((ext_vector_type(4)));

__device__ __forceinline__ h2_t as_h2(unsigned u) {
  union { unsigned u; h2_t h; } v; v.u = u; return v.h;
}

__device__ __forceinline__ float fdot2(h2_t a, h2_t b, float c) {
#if __has_builtin(__builtin_amdgcn_fdot2)
  return __builtin_amdgcn_fdot2(a, b, c, false);
#else
  return c + (float)a.x * (float)b.x + (float)a.y * (float)b.y;
#endif
}

// ---- fused pack + hist: blocks [0,npack) transpose/pack x -> fp16,
// blocks [npack,..) decode indices -> rc + histogram ----
__global__ void pack_hist_kernel(const float* __restrict__ x, uint2* __restrict__ xh,
                                 const int* __restrict__ indices, int* __restrict__ cnt,
                                 int2* __restrict__ rc, int batch, int size, int E,
                                 int npx, int npack) {
  __shared__ float tile[64][65];
  int bid = blockIdx.x;
  if (bid < npack) {
    int bx = bid % npx, by = bid / npx;
    int c0 = bx * 64;
    int b0 = by * 64;
    int tx = threadIdx.x & 63, ty = threadIdx.x >> 6;
#pragma unroll
    for (int k = 0; k < 64; k += 4) {
      int b = b0 + ty + k, c = c0 + tx;
      if (b < batch && c < size) tile[ty + k][tx] = x[(size_t)b * size + c];
    }
    __syncthreads();
#pragma unroll
    for (int it = 0; it < 4; ++it) {
      int idx = it * 256 + threadIdx.x;
      int cn_local = idx >> 6;
      int bl = idx & 63;
      int c_node = (c0 >> 2) + cn_local;
      int b = b0 + bl;
      if (b < batch && (c_node * 4 + 3) < size) {
        union { _Float16 h[4]; uint2 u; } cv;
        cv.h[0] = (_Float16)tile[bl][cn_local * 4 + 0];
        cv.h[1] = (_Float16)tile[bl][cn_local * 4 + 1];
        cv.h[2] = (_Float16)tile[bl][cn_local * 4 + 2];
        cv.h[3] = (_Float16)tile[bl][cn_local * 4 + 3];
        xh[(size_t)c_node * batch + b] = cv.u;
      }
    }
  } else {
    int e = (bid - npack) * 256 + threadIdx.x;
    if (e < E) {
      int2 ij = *(const int2*)(indices + (size_t)e * 32);
      int r = ij.x >> 2, c = ij.y >> 2;
      rc[e] = make_int2(r, c);
      atomicAdd(&cnt[r], 1);
    }
  }
}

// ---- parallel scan: reduce -> wave-scan of partials -> final ----
__global__ void scan_reduce_kernel(const int* __restrict__ cnt, int* __restrict__ partial, int n) {
  __shared__ int sh[256];
  int i = blockIdx.x * 256 + threadIdx.x;
  sh[threadIdx.x] = (i < n) ? cnt[i] : 0;
  __syncthreads();
  for (int off = 128; off > 0; off >>= 1) {
    if (threadIdx.x < off) sh[threadIdx.x] += sh[threadIdx.x + off];
    __syncthreads();
  }
  if (threadIdx.x == 0) partial[blockIdx.x] = sh[0];
}

__global__ void scan_mid_kernel(const int* __restrict__ partial, int* __restrict__ offs, int nb) {
  int t = threadIdx.x;
  int v = (t < nb) ? partial[t] : 0;
  for (int d = 1; d < 64; d <<= 1) {
    int u = __shfl_up(v, d);
    if (t >= d) v += u;
  }
  if (t < nb) offs[t] = v;  // inclusive
}

__global__ void scan_final_kernel(const int* __restrict__ cnt, const int* __restrict__ offs,
                                  int* __restrict__ row_start, int n) {
  __shared__ int sh[256];
  int blk = blockIdx.x;
  int i = blk * 256 + threadIdx.x;
  int v = (i < n) ? cnt[i] : 0;
  sh[threadIdx.x] = v;
  __syncthreads();
  for (int off = 1; off < 256; off <<= 1) {
    int add = (threadIdx.x >= off) ? sh[threadIdx.x - off] : 0;
    __syncthreads();
    sh[threadIdx.x] += add;
    __syncthreads();
  }
  int base = (blk == 0) ? 0 : offs[blk - 1];
  if (i < n) row_start[i + 1] = sh[threadIdx.x] + base;
  if (blk == 0 && threadIdx.x == 0) row_start[0] = 0;
}

__global__ void scan_kernel(const int* __restrict__ cnt, int* __restrict__ row_start, int n) {
  __shared__ int buf[1024];
  __shared__ int carry_s;
  int t = threadIdx.x;
  if (t == 0) { carry_s = 0; row_start[0] = 0; }
  __syncthreads();
  for (int base = 0; base < n; base += 1024) {
    int v = (base + t < n) ? cnt[base + t] : 0;
    buf[t] = v;
    __syncthreads();
    for (int off = 1; off < 1024; off <<= 1) {
      int add = (t >= off) ? buf[t - off] : 0;
      __syncthreads();
      buf[t] += add;
      __syncthreads();
    }
    if (base + t < n) row_start[base + t + 1] = buf[t] + carry_s;
    __syncthreads();
    if (t == 0) carry_s += buf[1023];
    __syncthreads();
  }
}

// ---- fused scatter + vals fp16 conversion (CSR order), drops perm/reorder ----
__global__ void scatter_vals_kernel(const int2* __restrict__ rc, const int* __restrict__ row_start,
                                    int* __restrict__ cursor, const float* __restrict__ vals,
                                    int* __restrict__ col_sorted, _Float16* __restrict__ vals_h,
                                    int E) {
  int e = blockIdx.x * blockDim.x + threadIdx.x;
  if (e >= E) return;
  int2 v = rc[e];
  int pos = row_start[v.x] + atomicAdd(&cursor[v.x], 1);
  col_sorted[pos] = v.y;
  const float* src = vals + (size_t)e * 16;
  union { _Float16 h[8]; uint4 u; } w0, w1;
#pragma unroll
  for (int i = 0; i < 8; ++i) w0.h[i] = (_Float16)src[i];
#pragma unroll
  for (int i = 0; i < 8; ++i) w1.h[i] = (_Float16)src[8 + i];
  *(uint4*)(vals_h + (size_t)pos * 16) = w0.u;
  *(uint4*)(vals_h + (size_t)pos * 16 + 8) = w1.u;
}

// One edge, two batch elements (X = 4 fp16 of b0, then 4 fp16 of b1).
__device__ __forceinline__ void edge_acc2(const _Float16* __restrict__ vh, size_t p,
                                          uint4 X, float* __restrict__ a0,
                                          float* __restrict__ a1) {
  uint4 A = *(const uint4*)(vh + p * 16);      // rows 0,1 of V
  uint4 C = *(const uint4*)(vh + p * 16 + 8);  // rows 2,3 of V
  h2_t x01a = as_h2(X.x), x23a = as_h2(X.y);
  h2_t x01b = as_h2(X.z), x23b = as_h2(X.w);
  a0[0] = fdot2(as_h2(A.x), x01a, a0[0]); a0[0] = fdot2(as_h2(A.y), x23a, a0[0]);
  a0[1] = fdot2(as_h2(A.z), x01a, a0[1]); a0[1] = fdot2(as_h2(A.w), x23a, a0[1]);
  a0[2] = fdot2(as_h2(C.x), x01a, a0[2]); a0[2] = fdot2(as_h2(C.y), x23a, a0[2]);
  a0[3] = fdot2(as_h2(C.z), x01a, a0[3]); a0[3] = fdot2(as_h2(C.w), x23a, a0[3]);
  a1[0] = fdot2(as_h2(A.x), x01b, a1[0]); a1[0] = fdot2(as_h2(A.y), x23b, a1[0]);
  a1[1] = fdot2(as_h2(A.z), x01b, a1[1]); a1[1] = fdot2(as_h2(A.w), x23b, a1[1]);
  a1[2] = fdot2(as_h2(C.x), x01b, a1[2]); a1[2] = fdot2(as_h2(C.y), x23b, a1[2]);
  a1[3] = fdot2(as_h2(C.z), x01b, a1[3]); a1[3] = fdot2(as_h2(C.w), x23b, a1[3]);
}

struct Chunk { uint4 x0, x1, x2, x3; };

__device__ __forceinline__ Chunk issue_chunk(const int* __restrict__ cp, int base,
                                             const uint4* __restrict__ xb, int bhalf) {
  Chunk ch;
  int c0 = cp[base], c1 = cp[base + 1], c2 = cp[base + 2], c3 = cp[base + 3];
  ch.x0 = xb[(size_t)c0 * bhalf];
  ch.x1 = xb[(size_t)c1 * bhalf];
  ch.x2 = xb[(size_t)c2 * bhalf];
  ch.x3 = xb[(size_t)c3 * bhalf];
  return ch;
}

__device__ __forceinline__ void compute_chunk(const _Float16* __restrict__ vh, size_t p,
                                              const Chunk& ch, float* __restrict__ a0,
                                              float* __restrict__ a1) {
  edge_acc2(vh, p,     ch.x0, a0, a1);
  edge_acc2(vh, p + 1, ch.x1, a0, a1);
  edge_acc2(vh, p + 2, ch.x2, a0, a1);
  edge_acc2(vh, p + 3, ch.x3, a0, a1);
}

// spmm: block = 4 waves, each wave owns one quad (4 block-rows); all waves
// share one 128-batch window (2 batch elems / lane via uint4). Slot-minor
// grid. Depth-2 software pipeline: 8 gathers in flight (A/B chunk ping-pong).
// Epilogue: LDS transpose -> 256B-contiguous full-line nt stores.
__global__ __launch_bounds__(256) void spmm_kernel(
    const int* __restrict__ row_start, const int* __restrict__ col_sorted,
    const _Float16* __restrict__ vals_h, const uint4* __restrict__ xh4,
    const float* __restrict__ biases, float* __restrict__ out,
    int n_nodes, int batch, int size, int nwin) {
  __shared__ float tile[64][68];
  int bx = blockIdx.x;
  int w = bx % nwin;
  int qg = bx / nwin;
  int wave = threadIdx.x >> 6;
  int lane = threadIdx.x & 63;
  int quad = qg * 4 + wave;
  bool qvalid = (quad * 4 < n_nodes);
  int bhalf = batch >> 1;  // batch pairs
  int bh = w * 64 + lane;
  bool bvalid = (bh < bhalf);
  int bhc = bvalid ? bh : bhalf - 1;
  const uint4* __restrict__ xb = xh4 + bhc;

  float acc[4][2][4];
#pragma unroll
  for (int i = 0; i < 32; ++i) ((float*)acc)[i] = 0.f;

  if (qvalid) {
#pragma unroll
    for (int rr = 0; rr < 4; ++rr) {
      int r = quad * 4 + rr;
      if (r >= n_nodes) break;
      int s = __builtin_amdgcn_readfirstlane(row_start[r]);
      int e = __builtin_amdgcn_readfirstlane(row_start[r + 1]);
      float* a0 = acc[rr][0];
      float* a1 = acc[rr][1];
      const int* cp = col_sorted + s;
      int len = e - s;
      int nch = len >> 2;
      // depth-2 pipeline over 4-edge chunks (static A/B slots)
      Chunk A, B;
      int j = 0;
      if (nch > 0) A = issue_chunk(cp, 0, xb, bhalf);
      while (j + 1 < nch) {
        B = issue_chunk(cp, (j + 1) * 4, xb, bhalf);
        compute_chunk(vals_h, (size_t)s + (size_t)j * 4, A, a0, a1);
        if (j + 2 < nch) A = issue_chunk(cp, (j + 2) * 4, xb, bhalf);
        compute_chunk(vals_h, (size_t)s + (size_t)(j + 1) * 4, B, a0, a1);
        j += 2;
      }
      if (j < nch) compute_chunk(vals_h, (size_t)s + (size_t)j * 4, A, a0, a1);
      for (int p = s + nch * 4; p < e; ++p) {
        uint4 X = xb[(size_t)cp[p - s] * bhalf];
        edge_acc2(vals_h, (size_t)p, X, a0, a1);
      }
    }
  }

  // ---- epilogue: two phases of 64 batch elements each ----
#pragma unroll
  for (int ph = 0; ph < 2; ++ph) {
    __syncthreads();
    if (qvalid && bvalid && (lane >> 5) == ph) {
      int lb = lane & 31;
#pragma unroll
      for (int rr = 0; rr < 4; ++rr) {
        int r = quad * 4 + rr;
        if (r < n_nodes) {
          float4 bias = *(const float4*)&biases[r << 2];
#pragma unroll
          for (int j = 0; j < 2; ++j) {
            float4 o = make_float4(acc[rr][j][0] + bias.x, acc[rr][j][1] + bias.y,
                                   acc[rr][j][2] + bias.z, acc[rr][j][3] + bias.w);
            *(float4*)&tile[lb * 2 + j][wave * 16 + rr * 4] = o;
          }
        }
      }
    }
    __syncthreads();
#pragma unroll
    for (int it = 0; it < 4; ++it) {
      int idx = it * 256 + threadIdx.x;
      int bl = idx >> 4;
      int f4 = idx & 15;
      int r = qg * 16 + f4;
      int b = w * 128 + ph * 64 + bl;
      if (r < n_nodes && b < batch) {
        f4_t v = *(f4_t*)&tile[bl][f4 * 4];
        __builtin_nontemporal_store(v, (f4_t*)&out[(size_t)b * size + (size_t)r * 4]);
      }
    }
  }
}

// Fallback when ws can't hold xh: gather fp32 x directly, fp16 V.
__global__ __launch_bounds__(256) void spmm_fb_kernel(
    const int* __restrict__ row_start, const int* __restrict__ col_sorted,
    const _Float16* __restrict__ vals_h, const float* __restrict__ x,
    const float* __restrict__ biases, float* __restrict__ out,
    int n_nodes, int batch, int size) {
  int quad = blockIdx.x;
  int b = blockIdx.y * blockDim.x + threadIdx.x;
  if (b >= batch || quad * 4 >= n_nodes) return;
  float acc[4][4];
#pragma unroll
  for (int i = 0; i < 16; ++i) ((float*)acc)[i] = 0.f;
#pragma unroll
  for (int rr = 0; rr < 4; ++rr) {
    int r = quad * 4 + rr;
    if (r >= n_nodes) break;
    int s = row_start[r], e = row_start[r + 1];
    for (int p = s; p < e; ++p) {
      int c = col_sorted[p];
      float4 xv = *(const float4*)&x[(size_t)b * size + (c << 2)];
      const _Float16* V = vals_h + (size_t)p * 16;
#pragma unroll
      for (int i = 0; i < 4; ++i) {
        acc[rr][i] += (float)V[i * 4 + 0] * xv.x + (float)V[i * 4 + 1] * xv.y +
                      (float)V[i * 4 + 2] * xv.z + (float)V[i * 4 + 3] * xv.w;
      }
    }
  }
#pragma unroll
  for (int rr = 0; rr < 4; ++rr) {
    int r = quad * 4 + rr;
    if (r >= n_nodes) break;
    float4 bias = *(const float4*)&biases[r << 2];
    float4 o = make_float4(acc[rr][0] + bias.x, acc[rr][1] + bias.y,
                           acc[rr][2] + bias.z, acc[rr][3] + bias.w);
    *(float4*)&out[(size_t)b * size + (r << 2)] = o;
  }
}

// Last-resort fallback (tiny ws)
__global__ void bias_init_kernel(float* __restrict__ out, const float* __restrict__ biases,
                                 int batch, int size) {
  size_t t = (size_t)blockIdx.x * blockDim.x + threadIdx.x;
  size_t total = (size_t)batch * size;
  if (t >= total) return;
  out[t] = biases[t % size];
}

__global__ void atomic_spmm_kernel(const int* __restrict__ indices, const float* __restrict__ vals,
                                   const float* __restrict__ x, float* __restrict__ out,
                                   int nnz, int batch, int size) {
  int n = blockIdx.x;
  if (n >= nnz) return;
  int i = indices[(size_t)n * 2];
  int j = indices[(size_t)n * 2 + 1];
  float v = vals[n];
  for (int b = threadIdx.x; b < batch; b += blockDim.x) {
    atomicAdd(&out[(size_t)b * size + i], v * x[(size_t)b * size + j]);
  }
}

extern "C" void kernel_launch(void* const* d_in, const int* in_sizes, int n_in,
                              void* d_out, int out_size, void* d_ws, size_t ws_size,
                              hipStream_t stream) {
  const float* x       = (const float*)d_in[0];
  const float* values  = (const float*)d_in[1];
  const float* biases  = (const float*)d_in[2];
  const int*   indices = (const int*)d_in[3];
  float* out = (float*)d_out;

  const int size    = in_sizes[2];        // 40000
  const int nnz     = in_sizes[1];        // 5,120,000
  const int batch   = in_sizes[0] / size; // 1024
  const int E       = nnz / 16;           // 320,000
  const int n_nodes = size / 4;           // 10,000

  // ---- workspace layout ----
  char* ws = (char*)d_ws;
  size_t off = 0;
  int* cnt = (int*)(ws + off);        off += (size_t)n_nodes * 4;
  int* cursor = (int*)(ws + off);     off += (size_t)n_nodes * 4;
  int* row_start = (int*)(ws + off);  off += ((size_t)n_nodes + 1) * 4;
  off = (off + 255) & ~(size_t)255;
  int* partial = (int*)(ws + off);    off += 64 * 4;
  int* offs = (int*)(ws + off);       off += 64 * 4;
  off = (off + 255) & ~(size_t)255;
  int* col_sorted = (int*)(ws + off); off += (size_t)E * 4;
  off = (off + 255) & ~(size_t)255;
  int2* rc = (int2*)(ws + off);       off += (size_t)E * 8;
  off = (off + 255) & ~(size_t)255;
  _Float16* vals_h = (_Float16*)(ws + off); off += (size_t)E * 32;
  off = (off + 255) & ~(size_t)255;
  size_t need_csr = off;
  uint2* xh = (uint2*)(ws + off);
  off += (size_t)(size / 4) * batch * 8;
  size_t need_full = off;

  const int n_quads = (n_nodes + 3) / 4;
  const int nb = (n_nodes + 255) / 256;

  if (ws_size >= need_full && (batch & 1) == 0 && nb <= 64) {
    hipMemsetAsync(cnt, 0, (size_t)2 * n_nodes * 4, stream);  // cnt + cursor

    int npx = (size + 63) / 64;
    int npy = (batch + 63) / 64;
    int npack = npx * npy;
    int nhist = (E + 255) / 256;
    pack_hist_kernel<<<npack + nhist, 256, 0, stream>>>(x, xh, indices, cnt, rc,
                                                        batch, size, E, npx, npack);

    scan_reduce_kernel<<<nb, 256, 0, stream>>>(cnt, partial, n_nodes);
    scan_mid_kernel<<<1, 64, 0, stream>>>(partial, offs, nb);
    scan_final_kernel<<<nb, 256, 0, stream>>>(cnt, offs, row_start, n_nodes);

    scatter_vals_kernel<<<(E + 255) / 256, 256, 0, stream>>>(rc, row_start, cursor,
                                                             values, col_sorted, vals_h, E);

    int nqg = (n_quads + 3) / 4;          // quad-groups of 4 (1 per wave)
    int nwin = (batch / 2 + 63) / 64;     // 128-batch windows (64 pairs)
    spmm_kernel<<<nqg * nwin, 256, 0, stream>>>(row_start, col_sorted, vals_h,
                                                (const uint4*)xh, biases, out,
                                                n_nodes, batch, size, nwin);
  } else if (ws_size >= need_csr) {
    hipMemsetAsync(cnt, 0, (size_t)2 * n_nodes * 4, stream);
    int npx = (size + 63) / 64;
    // hist-only via fused kernel (npack = 0)
    pack_hist_kernel<<<(E + 255) / 256, 256, 0, stream>>>(x, xh, indices, cnt, rc,
                                                          batch, size, E, npx, 0);
    if (nb <= 64) {
      scan_reduce_kernel<<<nb, 256, 0, stream>>>(cnt, partial, n_nodes);
      scan_mid_kernel<<<1, 64, 0, stream>>>(partial, offs, nb);
      scan_final_kernel<<<nb, 256, 0, stream>>>(cnt, offs, row_start, n_nodes);
    } else {
      scan_kernel<<<1, 1024, 0, stream>>>(cnt, row_start, n_nodes);
    }
    scatter_vals_kernel<<<(E + 255) / 256, 256, 0, stream>>>(rc, row_start, cursor,
                                                             values, col_sorted, vals_h, E);
    dim3 grid(n_quads, (batch + 255) / 256);
    spmm_fb_kernel<<<grid, 256, 0, stream>>>(row_start, col_sorted, vals_h, x,
                                             biases, out, n_nodes, batch, size);
  } else {
    size_t total = (size_t)batch * size;
    bias_init_kernel<<<(total + 255) / 256, 256, 0, stream>>>(out, biases, batch, size);
    atomic_spmm_kernel<<<nnz, 256, 0, stream>>>(indices, values, x, out, nnz, batch, size);
  }
}